// Round 11
// baseline (2107.973 us; speedup 1.0000x reference)
//
#include <hip/hip_runtime.h>
#include <hip/hip_bf16.h>
#include <stdint.h>

#define NH 8

typedef uint16_t u16;
typedef uint32_t u32;
typedef __attribute__((ext_vector_type(2))) u32 u32x2;
typedef __attribute__((ext_vector_type(4))) u32 u32x4;
typedef __attribute__((ext_vector_type(8))) short s8b;    // 8 bf16 (4 VGPR)
typedef __attribute__((ext_vector_type(4))) float f32x4;

#if __has_builtin(__builtin_amdgcn_exp2f)
#define EXPS(x) __builtin_amdgcn_exp2f(x)
#define QSCALE 0.36067376022224085f   // 0.25 * log2(e)
#else
#define EXPS(x) __expf(x)
#define QSCALE 0.25f
#endif

// fp32 -> bf16 round-to-nearest-even
__device__ __forceinline__ u16 f2b(float f) {
    u32 u = __builtin_bit_cast(u32, f);
    u = (u + 0x7fffu + ((u >> 16) & 1u)) >> 16;
    return (u16)u;
}
// bf16 -> fp32
__device__ __forceinline__ float b2f(u16 u) {
    return __builtin_bit_cast(float, (u32)u << 16);
}
// pack two fp32 into 2 bf16 (round-half-away): lo=a, hi=b.
__device__ __forceinline__ u32 pkbf(float a, float b) {
    u32 ua = __builtin_bit_cast(u32, a) + 0x8000u;
    u32 ub = __builtin_bit_cast(u32, b) + 0x8000u;
    return __builtin_amdgcn_perm(ub, ua, 0x07060302);  // {ua.hi16, ub.hi16}
}

// PyTorch-style sinusoidal PE
__device__ __forceinline__ float pe_val(int pos, int d) {
    int j = d >> 1;
    float div = expf((float)j * -0.14391156831212787f);
    float ang = (float)pos * div;
    return (d & 1) ? cosf(ang) : sinf(ang);
}

__global__ void embed_kernel(const int* __restrict__ src, const float* __restrict__ emb,
                             u16* __restrict__ Sb) {
    int idx = blockIdx.x * 256 + threadIdx.x;
    int d = idx & 127;
    int n = idx >> 7;
    int i = n & 63;
    int tok = src[n];
    Sb[idx] = f2b(emb[tok * 128 + d] * 11.313708498984761f + pe_val(i, d));
}

__global__ void addpe_kernel(const float* __restrict__ tgt, u16* __restrict__ Tb) {
    int idx = blockIdx.x * 256 + threadIdx.x;
    int d = idx & 127;
    int n = idx >> 7;
    int i = n & 1023;
    Tb[idx] = f2b(tgt[idx] + pe_val(i, d));
}

struct CvtJobs { const float* src[10]; u16* dst[10]; int n[10]; };
__global__ void cvt_kernel(CvtJobs jb) {
    int e = blockIdx.y;
    int i = blockIdx.x * 256 + threadIdx.x;
    if (i < jb.n[e]) jb.dst[e][i] = f2b(jb.src[e][i]);
}

// ---------------------------------------------------------------------------
// LDS-staged MFMA GEMM with register prefetch of the next k-tile (round-10).
template <int RELU>
__global__ __launch_bounds__(256) void gemm_mfma(
    const u16* __restrict__ A, const u16* __restrict__ W,
    const float* __restrict__ bias, u16* __restrict__ C,
    int M, int N, int K, float qscale, int qcols,
    u16* __restrict__ vt, int vcol0, int sshift, int smask, int skv) {
    __shared__ __align__(16) u16 As[128 * 56];
    __shared__ __align__(16) u16 Bs[128 * 56];
    int tid = threadIdx.x;
    int lane = tid & 63, w = tid >> 6;
    int quad = lane >> 4, l15 = lane & 15;
    int m0 = blockIdx.y * 128, n0 = blockIdx.x * 128;
    int wm = (w & 1) * 64, wn = (w >> 1) * 64;
    int srow = tid >> 1, skof = (tid & 1) * 16;

    f32x4 acc[4][4];
#pragma unroll
    for (int i = 0; i < 4; i++)
#pragma unroll
        for (int j = 0; j < 4; j++)
#pragma unroll
            for (int r = 0; r < 4; r++) acc[i][j][r] = 0.f;

    const u16* ga = A + (size_t)(m0 + srow) * K + skof;
    const u16* gw = W + (size_t)(n0 + srow) * K + skof;
    s8b a0 = *(const s8b*)ga, a1 = *(const s8b*)(ga + 8);
    s8b w0 = *(const s8b*)gw, w1 = *(const s8b*)(gw + 8);

    for (int k0 = 0; k0 < K; k0 += 32) {
        __syncthreads();
        *(s8b*)(As + srow * 56 + skof) = a0;
        *(s8b*)(As + srow * 56 + skof + 8) = a1;
        *(s8b*)(Bs + srow * 56 + skof) = w0;
        *(s8b*)(Bs + srow * 56 + skof + 8) = w1;
        __syncthreads();
        if (k0 + 32 < K) {
            a0 = *(const s8b*)(ga + k0 + 32); a1 = *(const s8b*)(ga + k0 + 40);
            w0 = *(const s8b*)(gw + k0 + 32); w1 = *(const s8b*)(gw + k0 + 40);
        }
        s8b af[4], bfr[4];
#pragma unroll
        for (int i = 0; i < 4; i++) af[i] = *(const s8b*)(As + (wm + 16 * i + l15) * 56 + quad * 8);
#pragma unroll
        for (int j = 0; j < 4; j++) bfr[j] = *(const s8b*)(Bs + (wn + 16 * j + l15) * 56 + quad * 8);
#pragma unroll
        for (int i = 0; i < 4; i++)
#pragma unroll
            for (int j = 0; j < 4; j++)
                acc[i][j] = __builtin_amdgcn_mfma_f32_16x16x32_bf16(af[i], bfr[j], acc[i][j], 0, 0, 0);
    }

    if (vt && n0 == vcol0) {
#pragma unroll
        for (int j = 0; j < 4; j++) {
            int lc = wn + 16 * j + l15;
            int h = lc >> 4, n = lc & 15;
            float bv = bias[vcol0 + lc];
#pragma unroll
            for (int i = 0; i < 4; i++) {
                int row = m0 + wm + 16 * i + quad * 4;
                int b = row >> sshift, tok = row & smask;
                u32 lo = pkbf(acc[i][j][0] + bv, acc[i][j][1] + bv);
                u32 hi = pkbf(acc[i][j][2] + bv, acc[i][j][3] + bv);
                u32* p = (u32*)(vt + ((size_t)((b * 8 + h) * 16 + n)) * skv + tok);
                p[0] = lo; p[1] = hi;
            }
        }
        return;
    }
#pragma unroll
    for (int j = 0; j < 4; j++) {
        int col = n0 + wn + 16 * j + l15;
        float bv = bias[col];
        float sc = (col < qcols) ? qscale : 1.f;
#pragma unroll
        for (int i = 0; i < 4; i++) {
            int rbase = m0 + wm + 16 * i + quad * 4;
#pragma unroll
            for (int r = 0; r < 4; r++) {
                float v = (acc[i][j][r] + bv) * sc;
                if (RELU) v = fmaxf(v, 0.f);
                C[(size_t)(rbase + r) * N + col] = f2b(v);
            }
        }
    }
}

// ---------------------------------------------------------------------------
// LDS-staged GEMM (N=128) fused with residual-add + LayerNorm (round-10).
__global__ __launch_bounds__(256) void gemm_ln(
    const u16* __restrict__ A, const u16* __restrict__ W,
    const float* __restrict__ bias, const u16* __restrict__ X,
    const float* __restrict__ g, const float* __restrict__ bta,
    u16* __restrict__ Yb, int M, int K) {
    __shared__ __align__(16) u16 As[128 * 56];
    __shared__ __align__(16) u16 Bs[128 * 56];
    __shared__ float redS[128][2], redQ[128][2];
    int tid = threadIdx.x;
    int lane = tid & 63, w = tid >> 6;
    int quad = lane >> 4, l15 = lane & 15;
    int m0 = blockIdx.x * 128;
    int wm = (w & 1) * 64, wn = (w >> 1) * 64;
    int srow = tid >> 1, skof = (tid & 1) * 16;

    f32x4 acc[4][4];
#pragma unroll
    for (int i = 0; i < 4; i++)
#pragma unroll
        for (int j = 0; j < 4; j++)
#pragma unroll
            for (int r = 0; r < 4; r++) acc[i][j][r] = 0.f;

    const u16* ga = A + (size_t)(m0 + srow) * K + skof;
    const u16* gw = W + (size_t)srow * K + skof;
    s8b a0 = *(const s8b*)ga, a1 = *(const s8b*)(ga + 8);
    s8b w0 = *(const s8b*)gw, w1 = *(const s8b*)(gw + 8);

    for (int k0 = 0; k0 < K; k0 += 32) {
        __syncthreads();
        *(s8b*)(As + srow * 56 + skof) = a0;
        *(s8b*)(As + srow * 56 + skof + 8) = a1;
        *(s8b*)(Bs + srow * 56 + skof) = w0;
        *(s8b*)(Bs + srow * 56 + skof + 8) = w1;
        __syncthreads();
        if (k0 + 32 < K) {
            a0 = *(const s8b*)(ga + k0 + 32); a1 = *(const s8b*)(ga + k0 + 40);
            w0 = *(const s8b*)(gw + k0 + 32); w1 = *(const s8b*)(gw + k0 + 40);
        }
        s8b af[4], bfr[4];
#pragma unroll
        for (int i = 0; i < 4; i++) af[i] = *(const s8b*)(As + (wm + 16 * i + l15) * 56 + quad * 8);
#pragma unroll
        for (int j = 0; j < 4; j++) bfr[j] = *(const s8b*)(Bs + (wn + 16 * j + l15) * 56 + quad * 8);
#pragma unroll
        for (int i = 0; i < 4; i++)
#pragma unroll
            for (int j = 0; j < 4; j++)
                acc[i][j] = __builtin_amdgcn_mfma_f32_16x16x32_bf16(af[i], bfr[j], acc[i][j], 0, 0, 0);
    }

    float s_[4][4], q_[4][4];
#pragma unroll
    for (int i = 0; i < 4; i++)
#pragma unroll
        for (int r = 0; r < 4; r++) {
            int row = m0 + wm + 16 * i + quad * 4 + r;
            float s = 0.f, q = 0.f;
#pragma unroll
            for (int j = 0; j < 4; j++) {
                int col = wn + 16 * j + l15;
                float x = acc[i][j][r] + bias[col] + b2f(X[(size_t)row * 128 + col]);
                acc[i][j][r] = x;
                s += x; q += x * x;
            }
#pragma unroll
            for (int off = 1; off < 16; off <<= 1) {
                s += __shfl_xor(s, off);
                q += __shfl_xor(q, off);
            }
            s_[i][r] = s; q_[i][r] = q;
        }
    if (l15 == 0) {
#pragma unroll
        for (int i = 0; i < 4; i++)
#pragma unroll
            for (int r = 0; r < 4; r++) {
                int lrow = wm + 16 * i + quad * 4 + r;
                redS[lrow][wn >> 6] = s_[i][r];
                redQ[lrow][wn >> 6] = q_[i][r];
            }
    }
    __syncthreads();
#pragma unroll
    for (int i = 0; i < 4; i++)
#pragma unroll
        for (int r = 0; r < 4; r++) {
            int lrow = wm + 16 * i + quad * 4 + r;
            int row = m0 + lrow;
            float S2 = redS[lrow][0] + redS[lrow][1];
            float Q2 = redQ[lrow][0] + redQ[lrow][1];
            float mean = S2 * (1.f / 128.f);
            float var = Q2 * (1.f / 128.f) - mean * mean;
            float rstd = rsqrtf(var + 1e-5f);
#pragma unroll
            for (int j = 0; j < 4; j++) {
                int col = wn + 16 * j + l15;
                float y = (acc[i][j][r] - mean) * rstd * g[col] + bta[col];
                Yb[(size_t)row * 128 + col] = f2b(y);
            }
        }
}

// ---------------------------------------------------------------------------
// attn5: all-register MFMA flash attention, 16 queries/wave, zero LDS.
// Uses ONLY mfma_f32_16x16x32_bf16 (verified layouts).
// QK^T: two zero-padded MFMAs. Q B-frag is loop-invariant: quads 0,1 hold the
// 16 dh dims, quads 2,3 are zero (contraction k=16..31 contributes nothing).
// K A-frag rows permuted: logical row m <- physical key p(m)=8*(m>>2)+(m&3)
// (tile A) / +4 (tile B). Then S C-layout (col=l15=query, row=quad*4+r) gives
// lane (l15,quad): tileA reg r = key 8*quad+r, tileB reg r = key 8*quad+4+r
// -> exp+pack yields THIS lane's PV B-frag (k=quad*8+j) with no data movement.
// PV: Oa = mfma(A = V^T row l15 16B at j0+quad*8, B = packed P).
// L: 8 VALU adds/tile + 2 end shuffles. O: col=l15=query, row=quad*4+r=dim.
__global__ __launch_bounds__(256) void attn5(
    const u16* __restrict__ Qb, int qstride,
    const u16* __restrict__ Kb, int kstride, int koff,
    const u16* __restrict__ VT,
    u16* __restrict__ O, int SQ, int SKV) {
    int tid = threadIdx.x;
    int lane = tid & 63, w = tid >> 6;
    int quad = lane >> 4, l15 = lane & 15;
    int nqc = SQ / 64;
    int bid = blockIdx.x;
    int qc = bid % nqc;
    int h = (bid / nqc) % NH;
    int b = bid / (nqc * NH);
    int q0 = qc * 64 + w * 16;

    // Q B-frag: lane l15 = query, quad -> k=quad*8+j; quads 2,3 zero.
    s8b qf;
#pragma unroll
    for (int j = 0; j < 8; j++) qf[j] = 0;
    if (quad < 2)
        qf = *(const s8b*)(Qb + (size_t)(b * SQ + q0 + l15) * qstride + h * 16 + quad * 8);

    // K A-frag row permutation p(l15) = 8*(l15>>2) + (l15&3)
    int pa = ((l15 & 12) << 1) | (l15 & 3);
    const u16* ka = Kb + (size_t)(b * SKV + pa) * kstride + koff + h * 16 + (quad & 1) * 8;
    const u16* kb2 = ka + (size_t)4 * kstride;   // tile B: key p+4
    size_t kadv = (size_t)32 * kstride;
    const u16* vtb = VT + (size_t)((b * NH + h) * 16 + l15) * SKV + quad * 8;

    f32x4 z4;
#pragma unroll
    for (int r = 0; r < 4; r++) z4[r] = 0.f;
    f32x4 Oa = z4;
    float lsum = 0.f;

#pragma unroll 2
    for (int j0 = 0; j0 < SKV; j0 += 32) {
        s8b kfA = *(const s8b*)ka;
        s8b kfB = *(const s8b*)kb2;
        ka += kadv; kb2 += kadv;
        s8b vb = *(const s8b*)(vtb + j0);
        f32x4 SA = __builtin_amdgcn_mfma_f32_16x16x32_bf16(kfA, qf, z4, 0, 0, 0);
        f32x4 SB = __builtin_amdgcn_mfma_f32_16x16x32_bf16(kfB, qf, z4, 0, 0, 0);
        float e0 = EXPS(SA[0]), e1 = EXPS(SA[1]), e2 = EXPS(SA[2]), e3 = EXPS(SA[3]);
        float e4 = EXPS(SB[0]), e5 = EXPS(SB[1]), e6 = EXPS(SB[2]), e7 = EXPS(SB[3]);
        lsum += (e0 + e1) + (e2 + e3) + (e4 + e5) + (e6 + e7);
        u32x4 p;
        p[0] = pkbf(e0, e1); p[1] = pkbf(e2, e3);
        p[2] = pkbf(e4, e5); p[3] = pkbf(e6, e7);
        Oa = __builtin_amdgcn_mfma_f32_16x16x32_bf16(vb, __builtin_bit_cast(s8b, p), Oa, 0, 0, 0);
    }
    // reduce L across the 4 quads holding the same query l15
    lsum += __shfl_xor(lsum, 16);
    lsum += __shfl_xor(lsum, 32);
    float inv = 1.f / lsum;
    // O: lane (l15, quad) holds dims quad*4 + r for query q0+l15
    u16* op = O + (size_t)(b * SQ + q0 + l15) * 128 + h * 16 + quad * 4;
    u32x2 st;
    st[0] = pkbf(Oa[0] * inv, Oa[1] * inv);
    st[1] = pkbf(Oa[2] * inv, Oa[3] * inv);
    *(u32x2*)op = st;
}

// Standalone LN over 128 cols, bf16 input -> bf16 output.
__global__ void ln_bf(const u16* __restrict__ X,
                      const float* __restrict__ g, const float* __restrict__ bta,
                      u16* __restrict__ Yb) {
    int r = blockIdx.x;
    int lane = threadIdx.x;
    size_t base = (size_t)r * 128;
    float x0 = b2f(X[base + lane]), x1 = b2f(X[base + lane + 64]);
    float s = x0 + x1;
    for (int off = 32; off; off >>= 1) s += __shfl_xor(s, off);
    float mean = s * (1.f / 128.f);
    float d0 = x0 - mean, d1 = x1 - mean;
    float vs = d0 * d0 + d1 * d1;
    for (int off = 32; off; off >>= 1) vs += __shfl_xor(vs, off);
    float rstd = rsqrtf(vs * (1.f / 128.f) + 1e-5f);
    Yb[base + lane] = f2b(d0 * rstd * g[lane] + bta[lane]);
    Yb[base + lane + 64] = f2b(d1 * rstd * g[lane + 64] + bta[lane + 64]);
}

// Fused final LayerNorm + FC, one wave per row.
__global__ void ln_fc(const u16* __restrict__ X,
                      const float* __restrict__ g, const float* __restrict__ bta,
                      const float* __restrict__ w, const float* __restrict__ bb,
                      float* __restrict__ out) {
    int r = blockIdx.x;
    int lane = threadIdx.x;
    size_t base = (size_t)r * 128;
    float x0 = b2f(X[base + lane]), x1 = b2f(X[base + lane + 64]);
    float s = x0 + x1;
    for (int off = 32; off; off >>= 1) s += __shfl_xor(s, off);
    float mean = s * (1.f / 128.f);
    float d0 = x0 - mean, d1 = x1 - mean;
    float vs = d0 * d0 + d1 * d1;
    for (int off = 32; off; off >>= 1) vs += __shfl_xor(vs, off);
    float rstd = rsqrtf(vs * (1.f / 128.f) + 1e-5f);
    float y0 = d0 * rstd * g[lane] + bta[lane];
    float y1 = d1 * rstd * g[lane + 64] + bta[lane + 64];
    float acc = y0 * w[lane] + y1 * w[lane + 64];
    for (int off = 32; off; off >>= 1) acc += __shfl_xor(acc, off);
    if (lane == 0) out[r] = acc + bb[0];
}

// ---- launch helpers ----
static inline void gemm_b(const u16* A, const u16* W, const float* bias, u16* C,
                          int M, int N, int K, hipStream_t st, int qcols = 0,
                          u16* vt = nullptr, int vcol0 = 0, int sshift = 0, int skv = 0) {
    hipLaunchKernelGGL((gemm_mfma<0>), dim3(N / 128, M / 128), dim3(256), 0, st,
                       A, W, bias, C, M, N, K, QSCALE, qcols, vt, vcol0, sshift,
                       (1 << sshift) - 1, skv);
}
static inline void gemm_br(const u16* A, const u16* W, const float* bias, u16* C,
                           int M, int N, int K, hipStream_t st) {
    hipLaunchKernelGGL((gemm_mfma<1>), dim3(N / 128, M / 128), dim3(256), 0, st,
                       A, W, bias, C, M, N, K, 1.f, 0, (u16*)nullptr, 0, 0, 0, 0);
}
static inline void gemmln(const u16* A, const u16* W, const float* bias,
                          const u16* X, const float* g, const float* bta,
                          u16* Yb, int M, int K, hipStream_t st) {
    hipLaunchKernelGGL(gemm_ln, dim3(M / 128), dim3(256), 0, st,
                       A, W, bias, X, g, bta, Yb, M, K);
}

extern "C" void kernel_launch(void* const* d_in, const int* in_sizes, int n_in,
                              void* d_out, int out_size, void* d_ws, size_t ws_size,
                              hipStream_t stream) {
    const int B = 32, SSRC = 64, STGT = 1024, D = 128, DFF_ = 512, LE = 6, LD = 6;

    const int*   src = (const int*)d_in[0];
    const float* tgt = (const float*)d_in[1];
    const float* emb = (const float*)d_in[2];
    const float* enc_qkv_w = (const float*)d_in[3];
    const float* enc_qkv_b = (const float*)d_in[4];
    const float* enc_out_w = (const float*)d_in[5];
    const float* enc_out_b = (const float*)d_in[6];
    const float* enc_ln1_g = (const float*)d_in[7];
    const float* enc_ln1_b = (const float*)d_in[8];
    const float* enc_ff1_w = (const float*)d_in[9];
    const float* enc_ff1_b = (const float*)d_in[10];
    const float* enc_ff2_w = (const float*)d_in[11];
    const float* enc_ff2_b = (const float*)d_in[12];
    const float* enc_ln2_g = (const float*)d_in[13];
    const float* enc_ln2_b = (const float*)d_in[14];
    const float* enc_norm_g = (const float*)d_in[15];
    const float* enc_norm_b = (const float*)d_in[16];
    const float* dec_sa_qkv_w = (const float*)d_in[17];
    const float* dec_sa_qkv_b = (const float*)d_in[18];
    const float* dec_sa_out_w = (const float*)d_in[19];
    const float* dec_sa_out_b = (const float*)d_in[20];
    const float* dec_ln1_g = (const float*)d_in[21];
    const float* dec_ln1_b = (const float*)d_in[22];
    const float* dec_ca_qkv_w = (const float*)d_in[23];
    const float* dec_ca_qkv_b = (const float*)d_in[24];
    const float* dec_ca_out_w = (const float*)d_in[25];
    const float* dec_ca_out_b = (const float*)d_in[26];
    const float* dec_ln2_g = (const float*)d_in[27];
    const float* dec_ln2_b = (const float*)d_in[28];
    const float* dec_ff1_w = (const float*)d_in[29];
    const float* dec_ff1_b = (const float*)d_in[30];
    const float* dec_ff2_w = (const float*)d_in[31];
    const float* dec_ff2_b = (const float*)d_in[32];
    const float* dec_ln3_g = (const float*)d_in[33];
    const float* dec_ln3_b = (const float*)d_in[34];
    const float* dec_norm_g = (const float*)d_in[35];
    const float* dec_norm_b = (const float*)d_in[36];
    const float* fc_w = (const float*)d_in[37];
    const float* fc_b = (const float*)d_in[38];

    const int NT = B * STGT;   // 32768
    const int NS = B * SSRC;   // 2048

    // ---- workspace: bf16 activations ----
    u16* t_bf    = (u16*)d_ws;                   // 32768*128
    u16* s_bf    = t_bf + (size_t)NT * D;        // 2048*128
    u16* mem_bf  = s_bf + (size_t)NS * D;        // 2048*128
    u16* qkv_bf  = mem_bf + (size_t)NS * D;      // 32768*512
    u16* attno_bf = qkv_bf + (size_t)NT * DFF_;  // 32768*128
    u16* ckv_bf  = attno_bf + (size_t)NT * D;    // 2048*256
    u16* vt      = ckv_bf + (size_t)NS * 2 * D;  // B*NH*16*1024 + pad
    u16* wa      = vt + (size_t)B * NH * 16 * STGT + 16 * STGT;

    u16* w_enc_qkv = wa;                          int n_enc_qkv = LE * 3 * D * D;
    u16* w_enc_out = w_enc_qkv + n_enc_qkv;       int n_enc_out = LE * D * D;
    u16* w_enc_ff1 = w_enc_out + n_enc_out;       int n_enc_ff1 = LE * DFF_ * D;
    u16* w_enc_ff2 = w_enc_ff1 + n_enc_ff1;       int n_enc_ff2 = LE * D * DFF_;
    u16* w_sa_qkv  = w_enc_ff2 + n_enc_ff2;       int n_sa_qkv = LD * 3 * D * D;
    u16* w_sa_out  = w_sa_qkv + n_sa_qkv;         int n_sa_out = LD * D * D;
    u16* w_ca_qkv  = w_sa_out + n_sa_out;         int n_ca_qkv = LD * 3 * D * D;
    u16* w_ca_out  = w_ca_qkv + n_ca_qkv;         int n_ca_out = LD * D * D;
    u16* w_ff1     = w_ca_out + n_ca_out;         int n_ff1 = LD * DFF_ * D;
    u16* w_ff2     = w_ff1 + n_ff1;               int n_ff2 = LD * D * DFF_;

    CvtJobs jb;
    jb.src[0] = enc_qkv_w;    jb.dst[0] = w_enc_qkv; jb.n[0] = n_enc_qkv;
    jb.src[1] = enc_out_w;    jb.dst[1] = w_enc_out; jb.n[1] = n_enc_out;
    jb.src[2] = enc_ff1_w;    jb.dst[2] = w_enc_ff1; jb.n[2] = n_enc_ff1;
    jb.src[3] = enc_ff2_w;    jb.dst[3] = w_enc_ff2; jb.n[3] = n_enc_ff2;
    jb.src[4] = dec_sa_qkv_w; jb.dst[4] = w_sa_qkv;  jb.n[4] = n_sa_qkv;
    jb.src[5] = dec_sa_out_w; jb.dst[5] = w_sa_out;  jb.n[5] = n_sa_out;
    jb.src[6] = dec_ca_qkv_w; jb.dst[6] = w_ca_qkv;  jb.n[6] = n_ca_qkv;
    jb.src[7] = dec_ca_out_w; jb.dst[7] = w_ca_out;  jb.n[7] = n_ca_out;
    jb.src[8] = dec_ff1_w;    jb.dst[8] = w_ff1;     jb.n[8] = n_ff1;
    jb.src[9] = dec_ff2_w;    jb.dst[9] = w_ff2;     jb.n[9] = n_ff2;
    int maxn = n_enc_ff1;
    hipLaunchKernelGGL(cvt_kernel, dim3((maxn + 255) / 256, 10), dim3(256), 0, stream, jb);

    // ---------------- Encoder ----------------
    hipLaunchKernelGGL(embed_kernel, dim3(NS * D / 256), dim3(256), 0, stream, src, emb, s_bf);

    for (int i = 0; i < LE; i++) {
        gemm_b(s_bf, w_enc_qkv + (size_t)i * 3 * D * D, enc_qkv_b + (size_t)i * 3 * D,
               qkv_bf, NS, 3 * D, D, stream, 128, vt, 256, 6, SSRC);  // Q scaled, V->vt
        hipLaunchKernelGGL(attn5, dim3(B * NH * (SSRC / 64)), dim3(256), 0, stream,
                           qkv_bf, 3 * D, qkv_bf, 3 * D, D, vt, attno_bf, SSRC, SSRC);
        gemmln(attno_bf, w_enc_out + (size_t)i * D * D, enc_out_b + (size_t)i * D,
               s_bf, enc_ln1_g + (size_t)i * D, enc_ln1_b + (size_t)i * D, s_bf, NS, D, stream);
        gemm_br(s_bf, w_enc_ff1 + (size_t)i * DFF_ * D, enc_ff1_b + (size_t)i * DFF_,
                qkv_bf, NS, DFF_, D, stream);
        gemmln(qkv_bf, w_enc_ff2 + (size_t)i * D * DFF_, enc_ff2_b + (size_t)i * D,
               s_bf, enc_ln2_g + (size_t)i * D, enc_ln2_b + (size_t)i * D, s_bf, NS, DFF_, stream);
    }
    hipLaunchKernelGGL(ln_bf, dim3(NS), dim3(64), 0, stream,
                       s_bf, enc_norm_g, enc_norm_b, mem_bf);

    // ---------------- Decoder ----------------
    hipLaunchKernelGGL(addpe_kernel, dim3(NT * D / 256), dim3(256), 0, stream, tgt, t_bf);

    for (int i = 0; i < LD; i++) {
        // self-attention
        gemm_b(t_bf, w_sa_qkv + (size_t)i * 3 * D * D, dec_sa_qkv_b + (size_t)i * 3 * D,
               qkv_bf, NT, 3 * D, D, stream, 128, vt, 256, 10, STGT);  // Q scaled, V->vt
        hipLaunchKernelGGL(attn5, dim3(B * NH * (STGT / 64)), dim3(256), 0, stream,
                           qkv_bf, 3 * D, qkv_bf, 3 * D, D, vt, attno_bf, STGT, STGT);
        gemmln(attno_bf, w_sa_out + (size_t)i * D * D, dec_sa_out_b + (size_t)i * D,
               t_bf, dec_ln1_g + (size_t)i * D, dec_ln1_b + (size_t)i * D, t_bf, NT, D, stream);

        // cross-attention
        gemm_b(t_bf, w_ca_qkv + (size_t)i * 3 * D * D, dec_ca_qkv_b + (size_t)i * 3 * D,
               qkv_bf, NT, D, D, stream, 128);  // Q only, pre-scaled
        gemm_b(mem_bf, w_ca_qkv + (size_t)i * 3 * D * D + (size_t)D * D,
               dec_ca_qkv_b + (size_t)i * 3 * D + D, ckv_bf, NS, 2 * D, D, stream,
               0, vt, 128, 6, SSRC);  // K->ckv, V->vt
        hipLaunchKernelGGL(attn5, dim3(B * NH * (STGT / 64)), dim3(256), 0, stream,
                           qkv_bf, D, ckv_bf, 2 * D, 0, vt, attno_bf, STGT, SSRC);
        gemmln(attno_bf, w_ca_out + (size_t)i * D * D, dec_ca_out_b + (size_t)i * D,
               t_bf, dec_ln2_g + (size_t)i * D, dec_ln2_b + (size_t)i * D, t_bf, NT, D, stream);

        // FFN
        gemm_br(t_bf, w_ff1 + (size_t)i * DFF_ * D, dec_ff1_b + (size_t)i * DFF_,
                qkv_bf, NT, DFF_, D, stream);
        gemmln(qkv_bf, w_ff2 + (size_t)i * D * DFF_, dec_ff2_b + (size_t)i * D,
               t_bf, dec_ln3_g + (size_t)i * D, dec_ln3_b + (size_t)i * D, t_bf, NT, DFF_, stream);
    }

    hipLaunchKernelGGL(ln_fc, dim3(NT), dim3(64), 0, stream,
                       t_bf, dec_norm_g, dec_norm_b, fc_w, fc_b, (float*)d_out);
}

// Round 12
// 1268.062 us; speedup vs baseline: 1.6624x; 1.6624x over previous
//
#include <hip/hip_runtime.h>
#include <hip/hip_bf16.h>
#include <stdint.h>

#define NH 8

typedef uint16_t u16;
typedef uint32_t u32;
typedef __attribute__((ext_vector_type(2))) u32 u32x2;
typedef __attribute__((ext_vector_type(8))) short s8b;    // 8 bf16 (4 VGPR)
typedef __attribute__((ext_vector_type(4))) float f32x4;
typedef __attribute__((ext_vector_type(16))) float f32x16;

#if __has_builtin(__builtin_amdgcn_exp2f)
#define EXPS(x) __builtin_amdgcn_exp2f(x)
#define QSCALE 0.36067376022224085f   // 0.25 * log2(e)
#else
#define EXPS(x) __expf(x)
#define QSCALE 0.25f
#endif

// fp32 -> bf16 round-to-nearest-even
__device__ __forceinline__ u16 f2b(float f) {
    u32 u = __builtin_bit_cast(u32, f);
    u = (u + 0x7fffu + ((u >> 16) & 1u)) >> 16;
    return (u16)u;
}
// bf16 -> fp32
__device__ __forceinline__ float b2f(u16 u) {
    return __builtin_bit_cast(float, (u32)u << 16);
}
// pack two fp32 into 2 bf16 (round-half-away): lo=a, hi=b.
__device__ __forceinline__ u32 pkbf(float a, float b) {
    u32 ua = __builtin_bit_cast(u32, a) + 0x8000u;
    u32 ub = __builtin_bit_cast(u32, b) + 0x8000u;
    return __builtin_amdgcn_perm(ub, ua, 0x07060302);  // {ua.hi16, ub.hi16}
}
// truncating pack (1 VALU op). Used ONLY for attention P: L is accumulated
// from the same truncated P, so normalization cancels the bias.
__device__ __forceinline__ u32 pkbf_t(float a, float b) {
    return __builtin_amdgcn_perm(__builtin_bit_cast(u32, b),
                                 __builtin_bit_cast(u32, a), 0x07060302);
}

// PyTorch-style sinusoidal PE
__device__ __forceinline__ float pe_val(int pos, int d) {
    int j = d >> 1;
    float div = expf((float)j * -0.14391156831212787f);
    float ang = (float)pos * div;
    return (d & 1) ? cosf(ang) : sinf(ang);
}

__global__ void embed_kernel(const int* __restrict__ src, const float* __restrict__ emb,
                             u16* __restrict__ Sb) {
    int idx = blockIdx.x * 256 + threadIdx.x;
    int d = idx & 127;
    int n = idx >> 7;
    int i = n & 63;
    int tok = src[n];
    Sb[idx] = f2b(emb[tok * 128 + d] * 11.313708498984761f + pe_val(i, d));
}

__global__ void addpe_kernel(const float* __restrict__ tgt, u16* __restrict__ Tb) {
    int idx = blockIdx.x * 256 + threadIdx.x;
    int d = idx & 127;
    int n = idx >> 7;
    int i = n & 1023;
    Tb[idx] = f2b(tgt[idx] + pe_val(i, d));
}

struct CvtJobs { const float* src[10]; u16* dst[10]; int n[10]; };
__global__ void cvt_kernel(CvtJobs jb) {
    int e = blockIdx.y;
    int i = blockIdx.x * 256 + threadIdx.x;
    if (i < jb.n[e]) jb.dst[e][i] = f2b(jb.src[e][i]);
}

// ---------------------------------------------------------------------------
// LDS-staged MFMA GEMM with register prefetch of the next k-tile (round-10).
template <int RELU>
__global__ __launch_bounds__(256) void gemm_mfma(
    const u16* __restrict__ A, const u16* __restrict__ W,
    const float* __restrict__ bias, u16* __restrict__ C,
    int M, int N, int K, float qscale, int qcols,
    u16* __restrict__ vt, int vcol0, int sshift, int smask, int skv) {
    __shared__ __align__(16) u16 As[128 * 56];
    __shared__ __align__(16) u16 Bs[128 * 56];
    int tid = threadIdx.x;
    int lane = tid & 63, w = tid >> 6;
    int quad = lane >> 4, l15 = lane & 15;
    int m0 = blockIdx.y * 128, n0 = blockIdx.x * 128;
    int wm = (w & 1) * 64, wn = (w >> 1) * 64;
    int srow = tid >> 1, skof = (tid & 1) * 16;

    f32x4 acc[4][4];
#pragma unroll
    for (int i = 0; i < 4; i++)
#pragma unroll
        for (int j = 0; j < 4; j++)
#pragma unroll
            for (int r = 0; r < 4; r++) acc[i][j][r] = 0.f;

    const u16* ga = A + (size_t)(m0 + srow) * K + skof;
    const u16* gw = W + (size_t)(n0 + srow) * K + skof;
    s8b a0 = *(const s8b*)ga, a1 = *(const s8b*)(ga + 8);
    s8b w0 = *(const s8b*)gw, w1 = *(const s8b*)(gw + 8);

    for (int k0 = 0; k0 < K; k0 += 32) {
        __syncthreads();
        *(s8b*)(As + srow * 56 + skof) = a0;
        *(s8b*)(As + srow * 56 + skof + 8) = a1;
        *(s8b*)(Bs + srow * 56 + skof) = w0;
        *(s8b*)(Bs + srow * 56 + skof + 8) = w1;
        __syncthreads();
        if (k0 + 32 < K) {
            a0 = *(const s8b*)(ga + k0 + 32); a1 = *(const s8b*)(ga + k0 + 40);
            w0 = *(const s8b*)(gw + k0 + 32); w1 = *(const s8b*)(gw + k0 + 40);
        }
        s8b af[4], bfr[4];
#pragma unroll
        for (int i = 0; i < 4; i++) af[i] = *(const s8b*)(As + (wm + 16 * i + l15) * 56 + quad * 8);
#pragma unroll
        for (int j = 0; j < 4; j++) bfr[j] = *(const s8b*)(Bs + (wn + 16 * j + l15) * 56 + quad * 8);
#pragma unroll
        for (int i = 0; i < 4; i++)
#pragma unroll
            for (int j = 0; j < 4; j++)
                acc[i][j] = __builtin_amdgcn_mfma_f32_16x16x32_bf16(af[i], bfr[j], acc[i][j], 0, 0, 0);
    }

    if (vt && n0 == vcol0) {
#pragma unroll
        for (int j = 0; j < 4; j++) {
            int lc = wn + 16 * j + l15;
            int h = lc >> 4, n = lc & 15;
            float bv = bias[vcol0 + lc];
#pragma unroll
            for (int i = 0; i < 4; i++) {
                int row = m0 + wm + 16 * i + quad * 4;
                int b = row >> sshift, tok = row & smask;
                u32 lo = pkbf(acc[i][j][0] + bv, acc[i][j][1] + bv);
                u32 hi = pkbf(acc[i][j][2] + bv, acc[i][j][3] + bv);
                u32* p = (u32*)(vt + ((size_t)((b * 8 + h) * 16 + n)) * skv + tok);
                p[0] = lo; p[1] = hi;
            }
        }
        return;
    }
#pragma unroll
    for (int j = 0; j < 4; j++) {
        int col = n0 + wn + 16 * j + l15;
        float bv = bias[col];
        float sc = (col < qcols) ? qscale : 1.f;
#pragma unroll
        for (int i = 0; i < 4; i++) {
            int rbase = m0 + wm + 16 * i + quad * 4;
#pragma unroll
            for (int r = 0; r < 4; r++) {
                float v = (acc[i][j][r] + bv) * sc;
                if (RELU) v = fmaxf(v, 0.f);
                C[(size_t)(rbase + r) * N + col] = f2b(v);
            }
        }
    }
}

// ---------------------------------------------------------------------------
// GEMM (N=128) fused with residual-add + LayerNorm; 64-row tiles for 2x grid
// occupancy (N=128 GEMMs were 1 block/CU at 128-row tiles). Each of 4 waves
// computes 32 rows x 64 cols (AI=2, BJ=4). bf16 residual stream.
__global__ __launch_bounds__(256) void gemm_ln(
    const u16* __restrict__ A, const u16* __restrict__ W,
    const float* __restrict__ bias, const u16* __restrict__ X,
    const float* __restrict__ g, const float* __restrict__ bta,
    u16* __restrict__ Yb, int M, int K) {
    __shared__ __align__(16) u16 As[64 * 56];
    __shared__ __align__(16) u16 Bs[128 * 56];
    __shared__ float redS[64][2], redQ[64][2];
    int tid = threadIdx.x;
    int lane = tid & 63, w = tid >> 6;
    int quad = lane >> 4, l15 = lane & 15;
    int m0 = blockIdx.x * 64;
    int wm = (w & 1) * 32, wn = (w >> 1) * 64;
    int srowA = tid >> 2, skofA = (tid & 3) * 8;   // 64 rows x 32 elems
    int srowB = tid >> 1, skofB = (tid & 1) * 16;  // 128 rows x 32 elems

    f32x4 acc[2][4];
#pragma unroll
    for (int i = 0; i < 2; i++)
#pragma unroll
        for (int j = 0; j < 4; j++)
#pragma unroll
            for (int r = 0; r < 4; r++) acc[i][j][r] = 0.f;

    const u16* ga = A + (size_t)(m0 + srowA) * K + skofA;
    const u16* gw = W + (size_t)srowB * K + skofB;
    s8b a0 = *(const s8b*)ga;
    s8b w0 = *(const s8b*)gw, w1 = *(const s8b*)(gw + 8);

    for (int k0 = 0; k0 < K; k0 += 32) {
        __syncthreads();
        *(s8b*)(As + srowA * 56 + skofA) = a0;
        *(s8b*)(Bs + srowB * 56 + skofB) = w0;
        *(s8b*)(Bs + srowB * 56 + skofB + 8) = w1;
        __syncthreads();
        if (k0 + 32 < K) {
            a0 = *(const s8b*)(ga + k0 + 32);
            w0 = *(const s8b*)(gw + k0 + 32); w1 = *(const s8b*)(gw + k0 + 40);
        }
        s8b af[2], bfr[4];
#pragma unroll
        for (int i = 0; i < 2; i++) af[i] = *(const s8b*)(As + (wm + 16 * i + l15) * 56 + quad * 8);
#pragma unroll
        for (int j = 0; j < 4; j++) bfr[j] = *(const s8b*)(Bs + (wn + 16 * j + l15) * 56 + quad * 8);
#pragma unroll
        for (int i = 0; i < 2; i++)
#pragma unroll
            for (int j = 0; j < 4; j++)
                acc[i][j] = __builtin_amdgcn_mfma_f32_16x16x32_bf16(af[i], bfr[j], acc[i][j], 0, 0, 0);
    }

    float s_[2][4], q_[2][4];
#pragma unroll
    for (int i = 0; i < 2; i++)
#pragma unroll
        for (int r = 0; r < 4; r++) {
            int row = m0 + wm + 16 * i + quad * 4 + r;
            float s = 0.f, q = 0.f;
#pragma unroll
            for (int j = 0; j < 4; j++) {
                int col = wn + 16 * j + l15;
                float x = acc[i][j][r] + bias[col] + b2f(X[(size_t)row * 128 + col]);
                acc[i][j][r] = x;
                s += x; q += x * x;
            }
#pragma unroll
            for (int off = 1; off < 16; off <<= 1) {
                s += __shfl_xor(s, off);
                q += __shfl_xor(q, off);
            }
            s_[i][r] = s; q_[i][r] = q;
        }
    if (l15 == 0) {
#pragma unroll
        for (int i = 0; i < 2; i++)
#pragma unroll
            for (int r = 0; r < 4; r++) {
                int lrow = wm + 16 * i + quad * 4 + r;
                redS[lrow][wn >> 6] = s_[i][r];
                redQ[lrow][wn >> 6] = q_[i][r];
            }
    }
    __syncthreads();
#pragma unroll
    for (int i = 0; i < 2; i++)
#pragma unroll
        for (int r = 0; r < 4; r++) {
            int lrow = wm + 16 * i + quad * 4 + r;
            int row = m0 + lrow;
            float S2 = redS[lrow][0] + redS[lrow][1];
            float Q2 = redQ[lrow][0] + redQ[lrow][1];
            float mean = S2 * (1.f / 128.f);
            float var = Q2 * (1.f / 128.f) - mean * mean;
            float rstd = rsqrtf(var + 1e-5f);
#pragma unroll
            for (int j = 0; j < 4; j++) {
                int col = wn + 16 * j + l15;
                float y = (acc[i][j][r] - mean) * rstd * g[col] + bta[col];
                Yb[(size_t)row * 128 + col] = f2b(y);
            }
        }
}

// MFMA flash attention v3 (round-10 winner; P packed by truncation).
template <int WAVES>
__global__ __launch_bounds__(WAVES * 64) void attn3(
    const u16* __restrict__ Qb, int qstride,
    const u16* __restrict__ Kb, int kstride, int koff,
    const u16* __restrict__ VT,
    u16* __restrict__ O, int SQ, int SKV) {
    __shared__ __align__(16) u32 Ps[WAVES][32 * 20];
    int tid = threadIdx.x;
    int lane = tid & 63, w = tid >> 6;
    int quad = lane >> 4, l15 = lane & 15, l31 = lane & 31, half = lane >> 5;
    int nqc = SQ / (WAVES * 32);
    int bid = blockIdx.x;
    int qc = bid % nqc;
    int h = (bid / nqc) % NH;
    int b = bid / (nqc * NH);
    int q0 = qc * WAVES * 32 + w * 32;

    const u16* qp = Qb + (size_t)(b * SQ + q0 + l31) * qstride + h * 16 + half * 8;
    s8b qf = *(const s8b*)qp;
    s8b ones;
#pragma unroll
    for (int j = 0; j < 8; j++) ones[j] = (short)0x3F80;  // bf16 1.0

    const u16* vtb = VT + ((size_t)(b * NH + h) * 16 + l15) * SKV + quad * 8;
    const u16* kp = Kb + (size_t)(b * SKV + l31) * kstride + koff + h * 16 + half * 8;
    size_t kadv = (size_t)32 * kstride;

    f32x4 O0, O1, L0, L1;
#pragma unroll
    for (int r = 0; r < 4; r++) { O0[r] = 0.f; O1[r] = 0.f; L0[r] = 0.f; L1[r] = 0.f; }
    f32x16 z16;
#pragma unroll
    for (int r = 0; r < 16; r++) z16[r] = 0.f;

    u32* pw = Ps[w];
#pragma unroll 2
    for (int j0 = 0; j0 < SKV; j0 += 32) {
        s8b kf = *(const s8b*)kp;
        kp += kadv;
        s8b vb = *(const s8b*)(vtb + j0);
        f32x16 S = __builtin_amdgcn_mfma_f32_32x32x16_bf16(kf, qf, z16, 0, 0, 0);  // S^T
        // C-layout: col = q = lane&31; row = key = (r&3) + 8*(r>>2) + 4*half
#pragma unroll
        for (int g = 0; g < 4; g++) {
            float p0 = EXPS(S[4 * g + 0]);
            float p1 = EXPS(S[4 * g + 1]);
            float p2 = EXPS(S[4 * g + 2]);
            float p3 = EXPS(S[4 * g + 3]);
            u32x2 pk;
            pk[0] = pkbf_t(p0, p1);
            pk[1] = pkbf_t(p2, p3);
            *(u32x2*)(pw + l31 * 20 + 2 * half + 4 * g) = pk;  // ds_write_b64
        }
        __builtin_amdgcn_wave_barrier();  // wave-private LDS RAW ordering
        s8b pa0 = *(const s8b*)(pw + l15 * 20 + quad * 4);
        s8b pa1 = *(const s8b*)(pw + (16 + l15) * 20 + quad * 4);
        O0 = __builtin_amdgcn_mfma_f32_16x16x32_bf16(pa0, vb, O0, 0, 0, 0);
        O1 = __builtin_amdgcn_mfma_f32_16x16x32_bf16(pa1, vb, O1, 0, 0, 0);
        L0 = __builtin_amdgcn_mfma_f32_16x16x32_bf16(pa0, ones, L0, 0, 0, 0);
        L1 = __builtin_amdgcn_mfma_f32_16x16x32_bf16(pa1, ones, L1, 0, 0, 0);
    }
#pragma unroll
    for (int r = 0; r < 4; r++) {
        int q = b * SQ + q0 + quad * 4 + r;
        O[(size_t)q * 128 + h * 16 + l15] = f2b(O0[r] / L0[r]);
        O[(size_t)(q + 16) * 128 + h * 16 + l15] = f2b(O1[r] / L1[r]);
    }
}

// Standalone LN over 128 cols, bf16 input -> bf16 output.
__global__ void ln_bf(const u16* __restrict__ X,
                      const float* __restrict__ g, const float* __restrict__ bta,
                      u16* __restrict__ Yb) {
    int r = blockIdx.x;
    int lane = threadIdx.x;
    size_t base = (size_t)r * 128;
    float x0 = b2f(X[base + lane]), x1 = b2f(X[base + lane + 64]);
    float s = x0 + x1;
    for (int off = 32; off; off >>= 1) s += __shfl_xor(s, off);
    float mean = s * (1.f / 128.f);
    float d0 = x0 - mean, d1 = x1 - mean;
    float vs = d0 * d0 + d1 * d1;
    for (int off = 32; off; off >>= 1) vs += __shfl_xor(vs, off);
    float rstd = rsqrtf(vs * (1.f / 128.f) + 1e-5f);
    Yb[base + lane] = f2b(d0 * rstd * g[lane] + bta[lane]);
    Yb[base + lane + 64] = f2b(d1 * rstd * g[lane + 64] + bta[lane + 64]);
}

// Fused final LayerNorm + FC, one wave per row.
__global__ void ln_fc(const u16* __restrict__ X,
                      const float* __restrict__ g, const float* __restrict__ bta,
                      const float* __restrict__ w, const float* __restrict__ bb,
                      float* __restrict__ out) {
    int r = blockIdx.x;
    int lane = threadIdx.x;
    size_t base = (size_t)r * 128;
    float x0 = b2f(X[base + lane]), x1 = b2f(X[base + lane + 64]);
    float s = x0 + x1;
    for (int off = 32; off; off >>= 1) s += __shfl_xor(s, off);
    float mean = s * (1.f / 128.f);
    float d0 = x0 - mean, d1 = x1 - mean;
    float vs = d0 * d0 + d1 * d1;
    for (int off = 32; off; off >>= 1) vs += __shfl_xor(vs, off);
    float rstd = rsqrtf(vs * (1.f / 128.f) + 1e-5f);
    float y0 = d0 * rstd * g[lane] + bta[lane];
    float y1 = d1 * rstd * g[lane + 64] + bta[lane + 64];
    float acc = y0 * w[lane] + y1 * w[lane + 64];
    for (int off = 32; off; off >>= 1) acc += __shfl_xor(acc, off);
    if (lane == 0) out[r] = acc + bb[0];
}

// ---- launch helpers ----
static inline void gemm_b(const u16* A, const u16* W, const float* bias, u16* C,
                          int M, int N, int K, hipStream_t st, int qcols = 0,
                          u16* vt = nullptr, int vcol0 = 0, int sshift = 0, int skv = 0) {
    hipLaunchKernelGGL((gemm_mfma<0>), dim3(N / 128, M / 128), dim3(256), 0, st,
                       A, W, bias, C, M, N, K, QSCALE, qcols, vt, vcol0, sshift,
                       (1 << sshift) - 1, skv);
}
static inline void gemm_br(const u16* A, const u16* W, const float* bias, u16* C,
                           int M, int N, int K, hipStream_t st) {
    hipLaunchKernelGGL((gemm_mfma<1>), dim3(N / 128, M / 128), dim3(256), 0, st,
                       A, W, bias, C, M, N, K, 1.f, 0, (u16*)nullptr, 0, 0, 0, 0);
}
static inline void gemmln(const u16* A, const u16* W, const float* bias,
                          const u16* X, const float* g, const float* bta,
                          u16* Yb, int M, int K, hipStream_t st) {
    hipLaunchKernelGGL(gemm_ln, dim3(M / 64), dim3(256), 0, st,
                       A, W, bias, X, g, bta, Yb, M, K);
}

extern "C" void kernel_launch(void* const* d_in, const int* in_sizes, int n_in,
                              void* d_out, int out_size, void* d_ws, size_t ws_size,
                              hipStream_t stream) {
    const int B = 32, SSRC = 64, STGT = 1024, D = 128, DFF_ = 512, LE = 6, LD = 6;

    const int*   src = (const int*)d_in[0];
    const float* tgt = (const float*)d_in[1];
    const float* emb = (const float*)d_in[2];
    const float* enc_qkv_w = (const float*)d_in[3];
    const float* enc_qkv_b = (const float*)d_in[4];
    const float* enc_out_w = (const float*)d_in[5];
    const float* enc_out_b = (const float*)d_in[6];
    const float* enc_ln1_g = (const float*)d_in[7];
    const float* enc_ln1_b = (const float*)d_in[8];
    const float* enc_ff1_w = (const float*)d_in[9];
    const float* enc_ff1_b = (const float*)d_in[10];
    const float* enc_ff2_w = (const float*)d_in[11];
    const float* enc_ff2_b = (const float*)d_in[12];
    const float* enc_ln2_g = (const float*)d_in[13];
    const float* enc_ln2_b = (const float*)d_in[14];
    const float* enc_norm_g = (const float*)d_in[15];
    const float* enc_norm_b = (const float*)d_in[16];
    const float* dec_sa_qkv_w = (const float*)d_in[17];
    const float* dec_sa_qkv_b = (const float*)d_in[18];
    const float* dec_sa_out_w = (const float*)d_in[19];
    const float* dec_sa_out_b = (const float*)d_in[20];
    const float* dec_ln1_g = (const float*)d_in[21];
    const float* dec_ln1_b = (const float*)d_in[22];
    const float* dec_ca_qkv_w = (const float*)d_in[23];
    const float* dec_ca_qkv_b = (const float*)d_in[24];
    const float* dec_ca_out_w = (const float*)d_in[25];
    const float* dec_ca_out_b = (const float*)d_in[26];
    const float* dec_ln2_g = (const float*)d_in[27];
    const float* dec_ln2_b = (const float*)d_in[28];
    const float* dec_ff1_w = (const float*)d_in[29];
    const float* dec_ff1_b = (const float*)d_in[30];
    const float* dec_ff2_w = (const float*)d_in[31];
    const float* dec_ff2_b = (const float*)d_in[32];
    const float* dec_ln3_g = (const float*)d_in[33];
    const float* dec_ln3_b = (const float*)d_in[34];
    const float* dec_norm_g = (const float*)d_in[35];
    const float* dec_norm_b = (const float*)d_in[36];
    const float* fc_w = (const float*)d_in[37];
    const float* fc_b = (const float*)d_in[38];

    const int NT = B * STGT;   // 32768
    const int NS = B * SSRC;   // 2048

    // ---- workspace: bf16 activations ----
    u16* t_bf    = (u16*)d_ws;                   // 32768*128
    u16* s_bf    = t_bf + (size_t)NT * D;        // 2048*128
    u16* mem_bf  = s_bf + (size_t)NS * D;        // 2048*128
    u16* qkv_bf  = mem_bf + (size_t)NS * D;      // 32768*512
    u16* attno_bf = qkv_bf + (size_t)NT * DFF_;  // 32768*128
    u16* ckv_bf  = attno_bf + (size_t)NT * D;    // 2048*256
    u16* vt      = ckv_bf + (size_t)NS * 2 * D;  // B*NH*16*1024 + pad
    u16* wa      = vt + (size_t)B * NH * 16 * STGT + 16 * STGT;

    u16* w_enc_qkv = wa;                          int n_enc_qkv = LE * 3 * D * D;
    u16* w_enc_out = w_enc_qkv + n_enc_qkv;       int n_enc_out = LE * D * D;
    u16* w_enc_ff1 = w_enc_out + n_enc_out;       int n_enc_ff1 = LE * DFF_ * D;
    u16* w_enc_ff2 = w_enc_ff1 + n_enc_ff1;       int n_enc_ff2 = LE * D * DFF_;
    u16* w_sa_qkv  = w_enc_ff2 + n_enc_ff2;       int n_sa_qkv = LD * 3 * D * D;
    u16* w_sa_out  = w_sa_qkv + n_sa_qkv;         int n_sa_out = LD * D * D;
    u16* w_ca_qkv  = w_sa_out + n_sa_out;         int n_ca_qkv = LD * 3 * D * D;
    u16* w_ca_out  = w_ca_qkv + n_ca_qkv;         int n_ca_out = LD * D * D;
    u16* w_ff1     = w_ca_out + n_ca_out;         int n_ff1 = LD * DFF_ * D;
    u16* w_ff2     = w_ff1 + n_ff1;               int n_ff2 = LD * D * DFF_;

    CvtJobs jb;
    jb.src[0] = enc_qkv_w;    jb.dst[0] = w_enc_qkv; jb.n[0] = n_enc_qkv;
    jb.src[1] = enc_out_w;    jb.dst[1] = w_enc_out; jb.n[1] = n_enc_out;
    jb.src[2] = enc_ff1_w;    jb.dst[2] = w_enc_ff1; jb.n[2] = n_enc_ff1;
    jb.src[3] = enc_ff2_w;    jb.dst[3] = w_enc_ff2; jb.n[3] = n_enc_ff2;
    jb.src[4] = dec_sa_qkv_w; jb.dst[4] = w_sa_qkv;  jb.n[4] = n_sa_qkv;
    jb.src[5] = dec_sa_out_w; jb.dst[5] = w_sa_out;  jb.n[5] = n_sa_out;
    jb.src[6] = dec_ca_qkv_w; jb.dst[6] = w_ca_qkv;  jb.n[6] = n_ca_qkv;
    jb.src[7] = dec_ca_out_w; jb.dst[7] = w_ca_out;  jb.n[7] = n_ca_out;
    jb.src[8] = dec_ff1_w;    jb.dst[8] = w_ff1;     jb.n[8] = n_ff1;
    jb.src[9] = dec_ff2_w;    jb.dst[9] = w_ff2;     jb.n[9] = n_ff2;
    int maxn = n_enc_ff1;
    hipLaunchKernelGGL(cvt_kernel, dim3((maxn + 255) / 256, 10), dim3(256), 0, stream, jb);

    // ---------------- Encoder ----------------
    hipLaunchKernelGGL(embed_kernel, dim3(NS * D / 256), dim3(256), 0, stream, src, emb, s_bf);

    for (int i = 0; i < LE; i++) {
        gemm_b(s_bf, w_enc_qkv + (size_t)i * 3 * D * D, enc_qkv_b + (size_t)i * 3 * D,
               qkv_bf, NS, 3 * D, D, stream, 128, vt, 256, 6, SSRC);  // Q scaled, V->vt
        hipLaunchKernelGGL((attn3<2>), dim3(B * NH), dim3(128), 0, stream,
                           qkv_bf, 3 * D, qkv_bf, 3 * D, D, vt, attno_bf, SSRC, SSRC);
        gemmln(attno_bf, w_enc_out + (size_t)i * D * D, enc_out_b + (size_t)i * D,
               s_bf, enc_ln1_g + (size_t)i * D, enc_ln1_b + (size_t)i * D, s_bf, NS, D, stream);
        gemm_br(s_bf, w_enc_ff1 + (size_t)i * DFF_ * D, enc_ff1_b + (size_t)i * DFF_,
                qkv_bf, NS, DFF_, D, stream);
        gemmln(qkv_bf, w_enc_ff2 + (size_t)i * D * DFF_, enc_ff2_b + (size_t)i * D,
               s_bf, enc_ln2_g + (size_t)i * D, enc_ln2_b + (size_t)i * D, s_bf, NS, DFF_, stream);
    }
    hipLaunchKernelGGL(ln_bf, dim3(NS), dim3(64), 0, stream,
                       s_bf, enc_norm_g, enc_norm_b, mem_bf);

    // ---------------- Decoder ----------------
    hipLaunchKernelGGL(addpe_kernel, dim3(NT * D / 256), dim3(256), 0, stream, tgt, t_bf);

    for (int i = 0; i < LD; i++) {
        // self-attention
        gemm_b(t_bf, w_sa_qkv + (size_t)i * 3 * D * D, dec_sa_qkv_b + (size_t)i * 3 * D,
               qkv_bf, NT, 3 * D, D, stream, 128, vt, 256, 10, STGT);  // Q scaled, V->vt
        hipLaunchKernelGGL((attn3<4>), dim3(B * NH * (STGT / 128)), dim3(256), 0, stream,
                           qkv_bf, 3 * D, qkv_bf, 3 * D, D, vt, attno_bf, STGT, STGT);
        gemmln(attno_bf, w_sa_out + (size_t)i * D * D, dec_sa_out_b + (size_t)i * D,
               t_bf, dec_ln1_g + (size_t)i * D, dec_ln1_b + (size_t)i * D, t_bf, NT, D, stream);

        // cross-attention
        gemm_b(t_bf, w_ca_qkv + (size_t)i * 3 * D * D, dec_ca_qkv_b + (size_t)i * 3 * D,
               qkv_bf, NT, D, D, stream, 128);  // Q only, pre-scaled
        gemm_b(mem_bf, w_ca_qkv + (size_t)i * 3 * D * D + (size_t)D * D,
               dec_ca_qkv_b + (size_t)i * 3 * D + D, ckv_bf, NS, 2 * D, D, stream,
               0, vt, 128, 6, SSRC);  // K->ckv, V->vt
        hipLaunchKernelGGL((attn3<4>), dim3(B * NH * (STGT / 128)), dim3(256), 0, stream,
                           qkv_bf, D, ckv_bf, 2 * D, 0, vt, attno_bf, STGT, SSRC);
        gemmln(attno_bf, w_ca_out + (size_t)i * D * D, dec_ca_out_b + (size_t)i * D,
               t_bf, dec_ln2_g + (size_t)i * D, dec_ln2_b + (size_t)i * D, t_bf, NT, D, stream);

        // FFN
        gemm_br(t_bf, w_ff1 + (size_t)i * DFF_ * D, dec_ff1_b + (size_t)i * DFF_,
                qkv_bf, NT, DFF_, D, stream);
        gemmln(qkv_bf, w_ff2 + (size_t)i * D * DFF_, dec_ff2_b + (size_t)i * D,
               t_bf, dec_ln3_g + (size_t)i * D, dec_ln3_b + (size_t)i * D, t_bf, NT, DFF_, stream);
    }

    hipLaunchKernelGGL(ln_fc, dim3(NT), dim3(64), 0, stream,
                       t_bf, dec_norm_g, dec_norm_b, fc_w, fc_b, (float*)d_out);
}